// Round 1
// 70.538 us; speedup vs baseline: 1.0286x; 1.0286x over previous
//
#include <hip/hip_runtime.h>

// PhaseLinear: out[b,o] = sum_c coef[b,c] * (sum_i in[b,i]*W[c,o,i] + bias[c,o])
// Round 11: two-kernel structure.
//  K1 Convert: f32 -> bf16 (RNE, identical f2bits) ONCE into workspace, laid out
//     in MFMA-fragment order (16B granule per (frag,lane)) so the GEMM's loads
//     are perfectly coalesced 1KB dwordx4 per wave. 6MB read / 3MB written.
//  K2 GEMM: barrier-free main loop. 1024 blocks x 128 thr (2 waves: K-split).
//     Each wave: 32x16 output tile x 4 ctrl pts over K/2=256 (8 kblks of 32).
//     Per kblk: 2 A-frag + 4 W-frag coalesced loads + 8 MFMAs, register
//     double-buffered. ONE barrier total (K-split pair reduce via LDS), then
//     coef/bias blend epilogue (identical math/order to round-10 kernel).

#define BATCH 1024
#define IN_F  512
#define OUT_F 512

typedef unsigned short u16;
typedef u16    u16x8  __attribute__((ext_vector_type(8)));
typedef __bf16 bf16x8 __attribute__((ext_vector_type(8)));
typedef float  f32x4  __attribute__((ext_vector_type(4)));

// ws layout (16B granules):
//   A' : frag = btile*16 + kblk        (btile in [0,64), kblk in [0,16))
//        lane (q<<4)|m holds inp[btile*16+m][kblk*32 + q*8 + j], j=0..7
//        granule id = frag*64 + lane              -> 65536 granules = 1 MB
//   W' : frag = (otile*4 + c)*16 + kblk (otile in [0,32), c in [0,4))
//        lane (q<<4)|n holds wts[c][otile*16+n][kblk*32 + q*8 + j]
//        granule id = 65536 + frag*64 + lane      -> 131072 granules = 2 MB
#define A_GRANULES 65536
#define W_GRANULES 131072

__device__ __forceinline__ u16 f2bits(float f) {   // f32 -> bf16 bits, RNE
  union { float f; unsigned int u; } v; v.f = f;
  unsigned int u = v.u;
  unsigned int r = u + 0x7fffu + ((u >> 16) & 1u);
  return (u16)(r >> 16);
}

__global__ __launch_bounds__(256)
void Convert_kernel(const float* __restrict__ inp, const float* __restrict__ wts,
                    u16x8* __restrict__ ws) {
  const int s = blockIdx.x * 256 + threadIdx.x;     // one 16B granule per thread
  const float* src;
  if (s < A_GRANULES) {
    const int frag = s >> 6, l = s & 63;
    const int btile = frag >> 4, kblk = frag & 15;
    const int m = l & 15, qq = l >> 4;
    src = inp + (size_t)(btile * 16 + m) * IN_F + kblk * 32 + qq * 8;
  } else {
    const int t = s - A_GRANULES;
    const int frag = t >> 6, l = t & 63;
    const int kblk = frag & 15, rest = frag >> 4;
    const int c = rest & 3, otile = rest >> 2;
    const int n = l & 15, qq = l >> 4;
    src = wts + ((size_t)c * OUT_F + otile * 16 + n) * IN_F + kblk * 32 + qq * 8;
  }
  const f32x4 v0 = *(const f32x4*)src;
  const f32x4 v1 = *(const f32x4*)(src + 4);
  u16x8 pk;
#pragma unroll
  for (int x = 0; x < 4; ++x) {
    pk[x]     = f2bits(v0[x]);
    pk[x + 4] = f2bits(v1[x]);
  }
  ws[s] = pk;                                       // fully coalesced 16B stores
}

__global__ __launch_bounds__(128)
void PhaseLinear_kernel(const u16x8* __restrict__ ws, const float* __restrict__ ph,
                        const float* __restrict__ bia, float* __restrict__ outp) {
  __shared__ f32x4 sRed[8][64];     // ks=1 partials; lanes stride 16B -> minimal conflict

  const int tid = threadIdx.x;
  const int ks  = tid >> 6;         // K-half (0/1), 256 each
  const int l   = tid & 63;
  const int q   = l >> 4;
  const int n   = l & 15;
  const int otile = blockIdx.x;     // 16 out features
  const int bty   = blockIdx.y;     // 32 batch rows (2 btiles)

  const bf16x8* __restrict__ A  = (const bf16x8*)ws;
  const bf16x8* __restrict__ Wp = (const bf16x8*)ws + A_GRANULES;

  // granule indices at kk=0
  const int ai0 = ((bty * 2 + 0) * 16 + ks * 8) * 64 + l;
  const int ai1 = ((bty * 2 + 1) * 16 + ks * 8) * 64 + l;
  int wi[4];
#pragma unroll
  for (int c = 0; c < 4; ++c) wi[c] = ((otile * 4 + c) * 16 + ks * 8) * 64 + l;

  bf16x8 a[2][2], w[2][4];
  a[0][0] = A[ai0];
  a[0][1] = A[ai1];
#pragma unroll
  for (int c = 0; c < 4; ++c) w[0][c] = Wp[wi[c]];

  f32x4 acc[2][4];
#pragma unroll
  for (int mi = 0; mi < 2; ++mi)
#pragma unroll
    for (int c = 0; c < 4; ++c) acc[mi][c] = (f32x4){0.f, 0.f, 0.f, 0.f};

#pragma unroll
  for (int kk = 0; kk < 8; ++kk) {
    const int cb = kk & 1, nb = cb ^ 1;
    if (kk < 7) {                                   // prefetch next kblk into regs
      const int off = (kk + 1) * 64;
      a[nb][0] = A[ai0 + off];
      a[nb][1] = A[ai1 + off];
#pragma unroll
      for (int c = 0; c < 4; ++c) w[nb][c] = Wp[wi[c] + off];
    }
#pragma unroll
    for (int mi = 0; mi < 2; ++mi)
#pragma unroll
      for (int c = 0; c < 4; ++c)
        acc[mi][c] = __builtin_amdgcn_mfma_f32_16x16x32_bf16(a[cb][mi], w[cb][c],
                                                             acc[mi][c], 0, 0, 0);
  }

  // --- K-split pair reduction (the only barrier in the kernel) ---
  if (ks == 1) {
#pragma unroll
    for (int mi = 0; mi < 2; ++mi)
#pragma unroll
      for (int c = 0; c < 4; ++c) sRed[mi * 4 + c][l] = acc[mi][c];
  }
  __syncthreads();

  if (ks == 0) {
    // C/D layout (m89/m91 verified): col = l&15, row = (l>>4)*4 + reg
    const float PI = 3.14159265358979323846f;
    const int o = otile * 16 + n;
    float bs[4];
#pragma unroll
    for (int c = 0; c < 4; ++c) bs[c] = bia[c * OUT_F + o];

#pragma unroll
    for (int mi = 0; mi < 2; ++mi) {
#pragma unroll
      for (int r = 0; r < 4; ++r) {
        const int b = bty * 32 + mi * 16 + q * 4 + r;
        const float p  = ph[b];
        const float t  = (p < 1.5f * PI) ? (p / (1.5f * PI)) : ((p - 0.5f * PI) / (1.5f * PI));
        const float t2 = t * t, t3 = t2 * t;
        const float c0 = t3 - 0.5f * t2;            // tt @ (0.5*CATMULL_ROM_BASIS)
        const float c1 = 1.0f - 2.5f * t3;
        const float c2 = 0.5f * t2 + 2.0f * t3;
        const float c3 = -0.5f * t3;
        const float s0 = acc[mi][0][r] + sRed[mi * 4 + 0][l][r];
        const float s1 = acc[mi][1][r] + sRed[mi * 4 + 1][l][r];
        const float s2 = acc[mi][2][r] + sRed[mi * 4 + 2][l][r];
        const float s3 = acc[mi][3][r] + sRed[mi * 4 + 3][l][r];
        outp[(size_t)b * OUT_F + o] =
            c0 * (s0 + bs[0]) + c1 * (s1 + bs[1]) + c2 * (s2 + bs[2]) + c3 * (s3 + bs[3]);
      }
    }
  }
}

extern "C" void kernel_launch(void* const* d_in, const int* in_sizes, int n_in,
                              void* d_out, int out_size, void* d_ws, size_t ws_size,
                              hipStream_t stream) {
  const float* inp = (const float*)d_in[0];   // input  (1024, 512) f32
  const float* ph  = (const float*)d_in[1];   // phase  (1024,)     f32
  const float* wts = (const float*)d_in[2];   // weights(4,512,512) f32
  const float* bia = (const float*)d_in[3];   // biases (4,512)     f32
  float* outp = (float*)d_out;                // out    (1024,512)  f32

  // K1: f32 -> bf16 fragment-ordered staging into workspace (3 MB used)
  Convert_kernel<<<dim3((A_GRANULES + W_GRANULES) / 256), 256, 0, stream>>>(
      inp, wts, (u16x8*)d_ws);

  // K2: barrier-free MFMA GEMM + blend epilogue
  dim3 grid(OUT_F / 16, BATCH / 32);          // (32, 32) = 1024 blocks x 128 thr
  PhaseLinear_kernel<<<grid, 128, 0, stream>>>((const u16x8*)d_ws, ph, bia, outp);
}